// Round 1
// baseline (281.386 us; speedup 1.0000x reference)
//
#include <hip/hip_runtime.h>
#include <hip/hip_bf16.h>
#include <cstdint>
#include <cstddef>

#define D_MODEL 768
#define D_STATE 16
#define BB      4
#define LL      2048
#define M_TOT   (BB*LL)      // 8192
#define NCHUNK  32
#define LCH     (LL/NCHUNK)  // 64

typedef __attribute__((ext_vector_type(8))) short bf16x8;
typedef __attribute__((ext_vector_type(4))) float f32x4;

__device__ __forceinline__ float clampf_(float x, float lo, float hi) {
    return fminf(fmaxf(x, lo), hi);
}
__device__ __forceinline__ float siluf_(float x) {
    return x / (1.f + __expf(-x));
}
// f32 -> bf16 round-to-nearest-even, as raw u16
__device__ __forceinline__ unsigned short f2bf(float f) {
    unsigned u = __float_as_uint(f);
    u += 0x7fffu + ((u >> 16) & 1u);
    return (unsigned short)(u >> 16);
}
// async global->LDS, 16 bytes per lane; lds base must be wave-uniform
__device__ __forceinline__ void gload16(void* lds, const void* g) {
    __builtin_amdgcn_global_load_lds(
        (const __attribute__((address_space(1))) void*)g,
        (__attribute__((address_space(3))) void*)lds, 16, 0, 0);
}

// ---------------- prep kernels ----------------

__global__ __launch_bounds__(256) void k_convert_x(const float* __restrict__ x,
                                                   unsigned short* __restrict__ xb, int n4) {
    int i = blockIdx.x * 256 + threadIdx.x;
    if (i >= n4) return;
    float4 v = ((const float4*)x)[i];
    ushort4 o;
    o.x = f2bf(v.x); o.y = f2bf(v.y); o.z = f2bf(v.z); o.w = f2bf(v.w);
    ((ushort4*)xb)[i] = o;
}

__global__ __launch_bounds__(256) void k_prep_A(const float* __restrict__ A_log,
                                                float* __restrict__ A_cl, int n) {
    int i = blockIdx.x * 256 + threadIdx.x;
    if (i < n) A_cl[i] = clampf_(-__expf(A_log[i]), -5.f, -0.1f);
}

// transpose R x C f32 -> C x R bf16 (R,C multiples of 32)
__global__ __launch_bounds__(256) void k_transpose_bf16(const float* __restrict__ src,
                                                        unsigned short* __restrict__ dst,
                                                        int R, int C) {
    __shared__ float tile[32][33];
    int tx = threadIdx.x & 31, ty = threadIdx.x >> 5;
    int c0 = blockIdx.x * 32, r0 = blockIdx.y * 32;
    #pragma unroll
    for (int rr = ty; rr < 32; rr += 8)
        tile[rr][tx] = src[(size_t)(r0 + rr) * C + c0 + tx];
    __syncthreads();
    #pragma unroll
    for (int rr = ty; rr < 32; rr += 8)
        dst[(size_t)(c0 + rr) * R + r0 + tx] = f2bf(tile[tx][rr]);
}

// ---------------- main bf16 MFMA GEMM ----------------
// C[M,N] = A[M,K](bf16) * Bt[N,K](bf16)^T + bias, with fused epilogue.
// EPI 0: W_in   -> n<768: x_main=silu(v) (f32+bf16); n>=768: gate=silu(v) (f32)
// EPI 1: W_delta-> delta = clip(softplus(v)+1e-4, 1e-4, 1) (f32)
// EPI 2: W_out  -> out = clip(v, -10, 10) (f32)
template<int EPI>
__global__ __launch_bounds__(256) void k_gemm(const unsigned short* __restrict__ A,
                                              const unsigned short* __restrict__ Bt,
                                              const float* __restrict__ bias,
                                              int K,
                                              float* __restrict__ out_f,
                                              unsigned short* __restrict__ out_b,
                                              float* __restrict__ out_f2) {
    __shared__ __align__(16) unsigned short As[128 * 32];
    __shared__ __align__(16) unsigned short Bs[128 * 32];
    const int tid = threadIdx.x;
    const int wave = tid >> 6, lane = tid & 63;
    const int wm = wave >> 1, wn = wave & 1;
    const int m0 = blockIdx.y * 128, n0 = blockIdx.x * 128;
    const int lr = lane & 15, lk = (lane >> 4) * 8;

    f32x4 acc[4][4] = {};

    for (int kt = 0; kt < K; kt += 32) {
        // stage A (128x32) and Bt-rows (128x32) into LDS, 16B/lane async
        #pragma unroll
        for (int p = 0; p < 2; ++p) {
            int ci = p * 256 + wave * 64 + lane;     // chunk id 0..511
            int row = ci >> 2, k8 = (ci & 3) * 8;
            const unsigned short* ga = &A [(size_t)(m0 + row) * K + kt + k8];
            const unsigned short* gb = &Bt[(size_t)(n0 + row) * K + kt + k8];
            gload16(&As[(p * 256 + wave * 64) * 8], ga);
            gload16(&Bs[(p * 256 + wave * 64) * 8], gb);
        }
        __syncthreads();   // vmcnt drain + barrier

        bf16x8 af[4], bfr[4];
        #pragma unroll
        for (int mt = 0; mt < 4; ++mt)
            af[mt] = *(const bf16x8*)&As[(wm * 64 + mt * 16 + lr) * 32 + lk];
        #pragma unroll
        for (int nt = 0; nt < 4; ++nt)
            bfr[nt] = *(const bf16x8*)&Bs[(wn * 64 + nt * 16 + lr) * 32 + lk];
        #pragma unroll
        for (int mt = 0; mt < 4; ++mt)
            #pragma unroll
            for (int nt = 0; nt < 4; ++nt)
                acc[mt][nt] = __builtin_amdgcn_mfma_f32_16x16x32_bf16(
                    af[mt], bfr[nt], acc[mt][nt], 0, 0, 0);
        __syncthreads();   // all waves done reading before restage
    }

    #pragma unroll
    for (int mt = 0; mt < 4; ++mt) {
        int row = m0 + wm * 64 + mt * 16 + (lane >> 4) * 4;
        #pragma unroll
        for (int nt = 0; nt < 4; ++nt) {
            int col = n0 + wn * 64 + nt * 16 + (lane & 15);
            #pragma unroll
            for (int i = 0; i < 4; ++i) {
                int r = row + i;
                float v = acc[mt][nt][i] + bias[col];
                if (EPI == 0) {
                    float s = siluf_(v);
                    if (col < D_MODEL) {
                        out_f[(size_t)r * D_MODEL + col] = s;
                        out_b[(size_t)r * D_MODEL + col] = f2bf(s);
                    } else {
                        out_f2[(size_t)r * D_MODEL + (col - D_MODEL)] = s;
                    }
                } else if (EPI == 1) {
                    float sp = (v > 20.f) ? v : log1pf(__expf(v));
                    out_f[(size_t)r * D_MODEL + col] = clampf_(sp + 1e-4f, 1e-4f, 1.f);
                } else {
                    out_f[(size_t)r * D_MODEL + col] = clampf_(v, -10.f, 10.f);
                }
            }
        }
    }
}

// ---------------- B/C projection (N=16+16, f32) ----------------
__global__ __launch_bounds__(256) void k_gemm_bc(const float* __restrict__ xm,
                                                 const float* __restrict__ WB,
                                                 const float* __restrict__ WC,
                                                 const float* __restrict__ bB,
                                                 const float* __restrict__ bC,
                                                 float* __restrict__ Bm,
                                                 float* __restrict__ Cm) {
    __shared__ float xr[8][D_MODEL];
    const int tid = threadIdx.x;
    const int r = tid >> 5, cidx = tid & 31;
    const size_t row0 = (size_t)blockIdx.x * 8;
    for (int i = tid; i < 8 * D_MODEL; i += 256) {
        int rr = i / D_MODEL, kk = i % D_MODEL;
        xr[rr][kk] = xm[(row0 + rr) * D_MODEL + kk];
    }
    __syncthreads();
    const float* W = (cidx < 16) ? WB : WC;
    const int cc = cidx & 15;
    float acc = 0.f;
    #pragma unroll 8
    for (int k = 0; k < D_MODEL; ++k)
        acc = fmaf(xr[r][k], W[k * 16 + cc], acc);
    acc += (cidx < 16) ? bB[cc] : bC[cc];
    if (cidx < 16) Bm[(row0 + r) * 16 + cc] = acc;
    else           Cm[(row0 + r) * 16 + cc] = acc;
}

// ---------------- chunked selective scan ----------------
// pass A: per (b, chunk, d) local scan from h=0; emit h_end, Aprod
__global__ __launch_bounds__(256) void k_scanA(const float* __restrict__ delta,
                                               const float* __restrict__ xm,
                                               const float* __restrict__ Bm,
                                               const float* __restrict__ A_cl,
                                               float* __restrict__ h_end,
                                               float* __restrict__ Aprod) {
    const int d = blockIdx.x * 256 + threadIdx.x;
    const int c = blockIdx.y, b = blockIdx.z;
    float Asv[16], h[16], ap[16];
    #pragma unroll
    for (int s = 0; s < 16; ++s) {
        Asv[s] = A_cl[s * D_MODEL + d];
        h[s] = 0.f; ap[s] = 1.f;
    }
    const int tbase = c * LCH;
    for (int tt = 0; tt < LCH; ++tt) {
        const size_t rowoff = (size_t)b * LL + tbase + tt;
        float dlt = delta[rowoff * D_MODEL + d];
        float xv  = xm[rowoff * D_MODEL + d];
        float dx = dlt * xv;
        const float* Bp = &Bm[rowoff * D_STATE];
        #pragma unroll
        for (int s = 0; s < 16; ++s) {
            float dA = clampf_(__expf(clampf_(dlt * Asv[s], -2.f, 0.f)), 0.05f, 1.f);
            float dBu = clampf_(dx * Bp[s], -5.f, 5.f);
            h[s] = clampf_(dA * h[s] + dBu, -100.f, 100.f);
            ap[s] *= dA;
        }
    }
    const size_t off = (((size_t)b * NCHUNK + c) * D_STATE) * D_MODEL + d;
    #pragma unroll
    for (int s = 0; s < 16; ++s) {
        h_end[off + (size_t)s * D_MODEL] = h[s];
        Aprod[off + (size_t)s * D_MODEL] = ap[s];
    }
}

// pass B: carry propagation across chunks per (b,s,d)
__global__ __launch_bounds__(256) void k_scanB(const float* __restrict__ h_end,
                                               const float* __restrict__ Aprod,
                                               float* __restrict__ h_in) {
    const int idx = blockIdx.x * 256 + threadIdx.x;  // 4*16*768 = 49152
    const int d = idx % D_MODEL;
    const int rest = idx / D_MODEL;
    const int s = rest & 15, b = rest >> 4;
    float hc = 0.f;
    for (int c = 0; c < NCHUNK; ++c) {
        const size_t off = (((size_t)b * NCHUNK + c) * D_STATE + s) * D_MODEL + d;
        h_in[off] = hc;
        hc = Aprod[off] * hc + h_end[off];
    }
}

// pass C: replay with true carry, fuse y = clip(sum_s h*C) + xm*D, * gate -> bf16
__global__ __launch_bounds__(256) void k_scanC(const float* __restrict__ delta,
                                               const float* __restrict__ xm,
                                               const float* __restrict__ Bm,
                                               const float* __restrict__ Cm,
                                               const float* __restrict__ A_cl,
                                               const float* __restrict__ h_in,
                                               const float* __restrict__ Dvec,
                                               const float* __restrict__ gate,
                                               unsigned short* __restrict__ ymid) {
    const int d = blockIdx.x * 256 + threadIdx.x;
    const int c = blockIdx.y, b = blockIdx.z;
    float Asv[16], h[16];
    const size_t coff = (((size_t)b * NCHUNK + c) * D_STATE) * D_MODEL + d;
    #pragma unroll
    for (int s = 0; s < 16; ++s) {
        Asv[s] = A_cl[s * D_MODEL + d];
        h[s] = h_in[coff + (size_t)s * D_MODEL];
    }
    const float Dv = Dvec[d];
    const int tbase = c * LCH;
    for (int tt = 0; tt < LCH; ++tt) {
        const size_t rowoff = (size_t)b * LL + tbase + tt;
        float dlt = delta[rowoff * D_MODEL + d];
        float xv  = xm[rowoff * D_MODEL + d];
        float dx = dlt * xv;
        const float* Bp = &Bm[rowoff * D_STATE];
        const float* Cp = &Cm[rowoff * D_STATE];
        float y = 0.f;
        #pragma unroll
        for (int s = 0; s < 16; ++s) {
            float dA = clampf_(__expf(clampf_(dlt * Asv[s], -2.f, 0.f)), 0.05f, 1.f);
            float dBu = clampf_(dx * Bp[s], -5.f, 5.f);
            h[s] = clampf_(dA * h[s] + dBu, -100.f, 100.f);
            y = fmaf(h[s], Cp[s], y);
        }
        y = clampf_(y, -10.f, 10.f);
        y = fmaf(xv, Dv, y);
        y *= gate[rowoff * D_MODEL + d];
        ymid[rowoff * D_MODEL + d] = f2bf(y);
    }
}

// ---------------- launch ----------------
extern "C" void kernel_launch(void* const* d_in, const int* in_sizes, int n_in,
                              void* d_out, int out_size, void* d_ws, size_t ws_size,
                              hipStream_t stream) {
    const float* x       = (const float*)d_in[0];
    const float* W_in    = (const float*)d_in[1];
    const float* b_in    = (const float*)d_in[2];
    const float* W_B     = (const float*)d_in[3];
    const float* b_B     = (const float*)d_in[4];
    const float* W_C     = (const float*)d_in[5];
    const float* b_C     = (const float*)d_in[6];
    const float* W_delta = (const float*)d_in[7];
    const float* b_delta = (const float*)d_in[8];
    const float* W_out   = (const float*)d_in[9];
    const float* b_out   = (const float*)d_in[10];
    const float* A_log   = (const float*)d_in[11];
    const float* Dvec    = (const float*)d_in[12];
    float* out = (float*)d_out;

    char* p = (char*)d_ws;
    auto alloc = [&](size_t bytes) {
        char* r = p;
        p += (bytes + 255) & ~(size_t)255;
        return r;
    };
    unsigned short* xb    = (unsigned short*)alloc((size_t)M_TOT * D_MODEL * 2);
    unsigned short* Wint  = (unsigned short*)alloc((size_t)2 * D_MODEL * D_MODEL * 2);
    unsigned short* Wdt   = (unsigned short*)alloc((size_t)D_MODEL * D_MODEL * 2);
    unsigned short* Wot   = (unsigned short*)alloc((size_t)D_MODEL * D_MODEL * 2);
    float*          xm_f  = (float*)alloc((size_t)M_TOT * D_MODEL * 4);
    unsigned short* xm_b  = (unsigned short*)alloc((size_t)M_TOT * D_MODEL * 2);
    float*          gate  = (float*)alloc((size_t)M_TOT * D_MODEL * 4);
    float*          dlt   = (float*)alloc((size_t)M_TOT * D_MODEL * 4);
    float*          Bm    = (float*)alloc((size_t)M_TOT * D_STATE * 4);
    float*          Cm    = (float*)alloc((size_t)M_TOT * D_STATE * 4);
    float*          A_cl  = (float*)alloc((size_t)D_STATE * D_MODEL * 4);
    float*          h_end = (float*)alloc((size_t)BB * NCHUNK * D_STATE * D_MODEL * 4);
    float*          Aprod = (float*)alloc((size_t)BB * NCHUNK * D_STATE * D_MODEL * 4);
    float*          h_in  = (float*)alloc((size_t)BB * NCHUNK * D_STATE * D_MODEL * 4);
    unsigned short* ymid  = (unsigned short*)alloc((size_t)M_TOT * D_MODEL * 2);

    // prep: convert x, A; transpose+convert weights
    k_convert_x<<<(M_TOT * D_MODEL / 4 + 255) / 256, 256, 0, stream>>>(x, xb, M_TOT * D_MODEL / 4);
    k_prep_A<<<(D_STATE * D_MODEL + 255) / 256, 256, 0, stream>>>(A_log, A_cl, D_STATE * D_MODEL);
    k_transpose_bf16<<<dim3(2 * D_MODEL / 32, D_MODEL / 32), 256, 0, stream>>>(W_in, Wint, D_MODEL, 2 * D_MODEL);
    k_transpose_bf16<<<dim3(D_MODEL / 32, D_MODEL / 32), 256, 0, stream>>>(W_delta, Wdt, D_MODEL, D_MODEL);
    k_transpose_bf16<<<dim3(D_MODEL / 32, D_MODEL / 32), 256, 0, stream>>>(W_out, Wot, D_MODEL, D_MODEL);

    // in-proj GEMM + silu split
    k_gemm<0><<<dim3(2 * D_MODEL / 128, M_TOT / 128), 256, 0, stream>>>(
        xb, Wint, b_in, D_MODEL, xm_f, xm_b, gate);
    // delta GEMM + softplus
    k_gemm<1><<<dim3(D_MODEL / 128, M_TOT / 128), 256, 0, stream>>>(
        xm_b, Wdt, b_delta, D_MODEL, dlt, nullptr, nullptr);
    // B/C projections
    k_gemm_bc<<<M_TOT / 8, 256, 0, stream>>>(xm_f, W_B, W_C, b_B, b_C, Bm, Cm);
    // chunked scan
    k_scanA<<<dim3(D_MODEL / 256, NCHUNK, BB), 256, 0, stream>>>(dlt, xm_f, Bm, A_cl, h_end, Aprod);
    k_scanB<<<(BB * D_STATE * D_MODEL) / 256, 256, 0, stream>>>(h_end, Aprod, h_in);
    k_scanC<<<dim3(D_MODEL / 256, NCHUNK, BB), 256, 0, stream>>>(
        dlt, xm_f, Bm, Cm, A_cl, h_in, Dvec, gate, ymid);
    // out-proj GEMM + clip
    k_gemm<2><<<dim3(D_MODEL / 128, M_TOT / 128), 256, 0, stream>>>(
        ymid, Wot, b_out, D_MODEL, out, nullptr, nullptr);
}

// Round 4
// 224.076 us; speedup vs baseline: 1.2558x; 1.2558x over previous
//
#include <hip/hip_runtime.h>
#include <hip/hip_bf16.h>
#include <cstdint>
#include <cstddef>

#define D_MODEL 768
#define D_STATE 16
#define BB      4
#define LL      2048
#define M_TOT   (BB*LL)      // 8192
#define NCHUNK  64
#define LCH     (LL/NCHUNK)  // 32
#define N_DBC   896          // 768 delta + 16 B + 16 C + 96 pad

typedef __attribute__((ext_vector_type(8))) short bf16x8;
typedef __attribute__((ext_vector_type(4))) float f32x4;

__device__ __forceinline__ float clampf_(float x, float lo, float hi) {
    return fminf(fmaxf(x, lo), hi);
}
__device__ __forceinline__ float siluf_(float x) {
    return x / (1.f + __expf(-x));
}
// f32 -> bf16 round-to-nearest-even, as raw u16
__device__ __forceinline__ unsigned short f2bf(float f) {
    unsigned u = __float_as_uint(f);
    u += 0x7fffu + ((u >> 16) & 1u);
    return (unsigned short)(u >> 16);
}
__device__ __forceinline__ float bf2f(unsigned short u) {
    return __uint_as_float(((unsigned)u) << 16);
}
// async global->LDS, 16 bytes per lane; lds base must be wave-uniform
__device__ __forceinline__ void gload16(void* lds, const void* g) {
    __builtin_amdgcn_global_load_lds(
        (const __attribute__((address_space(1))) void*)g,
        (__attribute__((address_space(3))) void*)lds, 16, 0, 0);
}

// ---------------- prep kernels ----------------

__global__ __launch_bounds__(256) void k_convert_x(const float* __restrict__ x,
                                                   unsigned short* __restrict__ xb, int n4) {
    int i = blockIdx.x * 256 + threadIdx.x;
    if (i >= n4) return;
    float4 v = ((const float4*)x)[i];
    ushort4 o;
    o.x = f2bf(v.x); o.y = f2bf(v.y); o.z = f2bf(v.z); o.w = f2bf(v.w);
    ((ushort4*)xb)[i] = o;
}

__global__ __launch_bounds__(256) void k_prep_A(const float* __restrict__ A_log,
                                                float* __restrict__ A_cl, int n) {
    int i = blockIdx.x * 256 + threadIdx.x;
    if (i < n) A_cl[i] = clampf_(-__expf(A_log[i]), -5.f, -0.1f);
}

// transpose R x C f32 -> C x R bf16 (R,C multiples of 32); dst row stride = R
__global__ __launch_bounds__(256) void k_transpose_bf16(const float* __restrict__ src,
                                                        unsigned short* __restrict__ dst,
                                                        int R, int C) {
    __shared__ float tile[32][33];
    int tx = threadIdx.x & 31, ty = threadIdx.x >> 5;
    int c0 = blockIdx.x * 32, r0 = blockIdx.y * 32;
    #pragma unroll
    for (int rr = ty; rr < 32; rr += 8)
        tile[rr][tx] = src[(size_t)(r0 + rr) * C + c0 + tx];
    __syncthreads();
    #pragma unroll
    for (int rr = ty; rr < 32; rr += 8)
        dst[(size_t)(c0 + rr) * R + r0 + tx] = f2bf(tile[tx][rr]);
}

// rows 768..895 of WdBC: W_B^T, W_C^T, zero-pad
__global__ __launch_bounds__(256) void k_fill_bc(const float* __restrict__ W_B,
                                                 const float* __restrict__ W_C,
                                                 unsigned short* __restrict__ WdBC) {
    int idx = blockIdx.x * 256 + threadIdx.x;     // 128*768
    if (idx >= 128 * D_MODEL) return;
    int r = idx / D_MODEL + D_MODEL, k = idx % D_MODEL;
    unsigned short v = 0;
    if (r < D_MODEL + 16)       v = f2bf(W_B[k * 16 + (r - D_MODEL)]);
    else if (r < D_MODEL + 32)  v = f2bf(W_C[k * 16 + (r - D_MODEL - 16)]);
    WdBC[(size_t)r * D_MODEL + k] = v;
}

__global__ __launch_bounds__(256) void k_bias_dbc(const float* __restrict__ b_delta,
                                                  const float* __restrict__ b_B,
                                                  const float* __restrict__ b_C,
                                                  float* __restrict__ bias) {
    int i = blockIdx.x * 256 + threadIdx.x;
    if (i >= N_DBC) return;
    float v = 0.f;
    if (i < D_MODEL)            v = b_delta[i];
    else if (i < D_MODEL + 16)  v = b_B[i - D_MODEL];
    else if (i < D_MODEL + 32)  v = b_C[i - D_MODEL - 16];
    bias[i] = v;
}

// ---------------- main bf16 MFMA GEMM ----------------
// C[M,N] = A[M,K](bf16) * Bt[N,K](bf16)^T + bias, fused epilogue.
// EPI 0: W_in   -> col<768: xm_b=silu bf16; col>=768: gate_b=silu bf16
// EPI 1: WdBC   -> col<768: dlt_b=clip(softplus+1e-4) bf16; 768..783: Bm f32; 784..799: Cm f32
// EPI 2: W_out  -> out_f = clip(v,-10,10) f32
template<int EPI>
__global__ __launch_bounds__(256) void k_gemm(const unsigned short* __restrict__ A,
                                              const unsigned short* __restrict__ Bt,
                                              const float* __restrict__ bias,
                                              int K,
                                              float* __restrict__ out_f,
                                              float* __restrict__ out_f2,
                                              unsigned short* __restrict__ out_b0,
                                              unsigned short* __restrict__ out_b1) {
    __shared__ __align__(16) unsigned short As[128 * 32];
    __shared__ __align__(16) unsigned short Bs[128 * 32];
    const int tid = threadIdx.x;
    const int wave = tid >> 6, lane = tid & 63;
    const int wm = wave >> 1, wn = wave & 1;
    const int m0 = blockIdx.y * 128, n0 = blockIdx.x * 128;
    const int lr = lane & 15, lk = (lane >> 4) * 8;

    f32x4 acc[4][4] = {};

    for (int kt = 0; kt < K; kt += 32) {
        #pragma unroll
        for (int p = 0; p < 2; ++p) {
            int ci = p * 256 + wave * 64 + lane;     // 0..511
            int row = ci >> 2, k8 = (ci & 3) * 8;
            const unsigned short* ga = &A [(size_t)(m0 + row) * K + kt + k8];
            const unsigned short* gb = &Bt[(size_t)(n0 + row) * K + kt + k8];
            gload16(&As[(p * 256 + wave * 64) * 8], ga);
            gload16(&Bs[(p * 256 + wave * 64) * 8], gb);
        }
        __syncthreads();

        bf16x8 af[4], bfr[4];
        #pragma unroll
        for (int mt = 0; mt < 4; ++mt)
            af[mt] = *(const bf16x8*)&As[(wm * 64 + mt * 16 + lr) * 32 + lk];
        #pragma unroll
        for (int nt = 0; nt < 4; ++nt)
            bfr[nt] = *(const bf16x8*)&Bs[(wn * 64 + nt * 16 + lr) * 32 + lk];
        #pragma unroll
        for (int mt = 0; mt < 4; ++mt)
            #pragma unroll
            for (int nt = 0; nt < 4; ++nt)
                acc[mt][nt] = __builtin_amdgcn_mfma_f32_16x16x32_bf16(
                    af[mt], bfr[nt], acc[mt][nt], 0, 0, 0);
        __syncthreads();
    }

    #pragma unroll
    for (int mt = 0; mt < 4; ++mt) {
        int row = m0 + wm * 64 + mt * 16 + (lane >> 4) * 4;
        #pragma unroll
        for (int nt = 0; nt < 4; ++nt) {
            int col = n0 + wn * 64 + nt * 16 + (lane & 15);
            #pragma unroll
            for (int i = 0; i < 4; ++i) {
                int r = row + i;
                float v = acc[mt][nt][i] + bias[col];
                if (EPI == 0) {
                    float s = siluf_(v);
                    if (col < D_MODEL) out_b0[(size_t)r * D_MODEL + col] = f2bf(s);
                    else               out_b1[(size_t)r * D_MODEL + (col - D_MODEL)] = f2bf(s);
                } else if (EPI == 1) {
                    if (col < D_MODEL) {
                        float sp = (v > 20.f) ? v : log1pf(__expf(v));
                        out_b0[(size_t)r * D_MODEL + col] = f2bf(clampf_(sp + 1e-4f, 1e-4f, 1.f));
                    } else if (col < D_MODEL + 16) {
                        out_f[(size_t)r * D_STATE + (col - D_MODEL)] = v;
                    } else if (col < D_MODEL + 32) {
                        out_f2[(size_t)r * D_STATE + (col - D_MODEL - 16)] = v;
                    }
                } else {
                    out_f[(size_t)r * D_MODEL + col] = clampf_(v, -10.f, 10.f);
                }
            }
        }
    }
}

// ---------------- chunked selective scan ----------------
// pass A: per (b, chunk, d) local scan from h=0; emit h_end, Aprod
__global__ __launch_bounds__(256) void k_scanA(const unsigned short* __restrict__ dlt,
                                               const unsigned short* __restrict__ xm,
                                               const float* __restrict__ Bm,
                                               const float* __restrict__ A_cl,
                                               float* __restrict__ h_end,
                                               float* __restrict__ Aprod) {
    const int d = blockIdx.x * 256 + threadIdx.x;
    const int c = blockIdx.y, b = blockIdx.z;
    __shared__ float Bsh[LCH][D_STATE];
    const int rowbase = b * LL + c * LCH;
    for (int i = threadIdx.x; i < LCH * D_STATE; i += 256)
        ((float*)Bsh)[i] = Bm[(size_t)rowbase * D_STATE + i];
    __syncthreads();

    float Asv[16], h[16], ap[16];
    #pragma unroll
    for (int s = 0; s < 16; ++s) {
        Asv[s] = A_cl[s * D_MODEL + d];
        h[s] = 0.f; ap[s] = 1.f;
    }
    for (int tt = 0; tt < LCH; ++tt) {
        const size_t rowoff = (size_t)(rowbase + tt);
        float dltv = bf2f(dlt[rowoff * D_MODEL + d]);
        float xv   = bf2f(xm [rowoff * D_MODEL + d]);
        float dx = dltv * xv;
        #pragma unroll
        for (int s = 0; s < 16; ++s) {
            float dA  = __expf(fmaxf(dltv * Asv[s], -2.f));
            float dBu = clampf_(dx * Bsh[tt][s], -5.f, 5.f);
            h[s] = clampf_(fmaf(dA, h[s], dBu), -100.f, 100.f);
            ap[s] *= dA;
        }
    }
    const size_t off = (((size_t)b * NCHUNK + c) * D_STATE) * D_MODEL + d;
    #pragma unroll
    for (int s = 0; s < 16; ++s) {
        h_end[off + (size_t)s * D_MODEL] = h[s];
        Aprod[off + (size_t)s * D_MODEL] = ap[s];
    }
}

// pass B: carry propagation across chunks per (b,s,d)
__global__ __launch_bounds__(256) void k_scanB(const float* __restrict__ h_end,
                                               const float* __restrict__ Aprod,
                                               float* __restrict__ h_in) {
    const int idx = blockIdx.x * 256 + threadIdx.x;  // 4*16*768 = 49152
    const int d = idx % D_MODEL;
    const int rest = idx / D_MODEL;
    const int s = rest & 15, b = rest >> 4;
    float hc = 0.f;
    for (int c = 0; c < NCHUNK; ++c) {
        const size_t off = (((size_t)b * NCHUNK + c) * D_STATE + s) * D_MODEL + d;
        h_in[off] = hc;
        hc = Aprod[off] * hc + h_end[off];
    }
}

// pass C: replay with true carry, fuse y = clip(sum_s h*C) + xm*D, * gate -> bf16
__global__ __launch_bounds__(256) void k_scanC(const unsigned short* __restrict__ dlt,
                                               const unsigned short* __restrict__ xm,
                                               const float* __restrict__ Bm,
                                               const float* __restrict__ Cm,
                                               const float* __restrict__ A_cl,
                                               const float* __restrict__ h_in,
                                               const float* __restrict__ Dvec,
                                               const unsigned short* __restrict__ gate,
                                               unsigned short* __restrict__ ymid) {
    const int d = blockIdx.x * 256 + threadIdx.x;
    const int c = blockIdx.y, b = blockIdx.z;
    __shared__ float Bsh[LCH][D_STATE];
    __shared__ float Csh[LCH][D_STATE];
    const int rowbase = b * LL + c * LCH;
    for (int i = threadIdx.x; i < LCH * D_STATE; i += 256) {
        ((float*)Bsh)[i] = Bm[(size_t)rowbase * D_STATE + i];
        ((float*)Csh)[i] = Cm[(size_t)rowbase * D_STATE + i];
    }
    __syncthreads();

    float Asv[16], h[16];
    const size_t coff = (((size_t)b * NCHUNK + c) * D_STATE) * D_MODEL + d;
    #pragma unroll
    for (int s = 0; s < 16; ++s) {
        Asv[s] = A_cl[s * D_MODEL + d];
        h[s] = h_in[coff + (size_t)s * D_MODEL];
    }
    const float Dv = Dvec[d];
    for (int tt = 0; tt < LCH; ++tt) {
        const size_t rowoff = (size_t)(rowbase + tt);
        float dltv = bf2f(dlt[rowoff * D_MODEL + d]);
        float xv   = bf2f(xm [rowoff * D_MODEL + d]);
        float dx = dltv * xv;
        float y = 0.f;
        #pragma unroll
        for (int s = 0; s < 16; ++s) {
            float dA  = __expf(fmaxf(dltv * Asv[s], -2.f));
            float dBu = clampf_(dx * Bsh[tt][s], -5.f, 5.f);
            h[s] = clampf_(fmaf(dA, h[s], dBu), -100.f, 100.f);
            y = fmaf(h[s], Csh[tt][s], y);
        }
        y = clampf_(y, -10.f, 10.f);
        y = fmaf(xv, Dv, y);
        y *= bf2f(gate[rowoff * D_MODEL + d]);
        ymid[rowoff * D_MODEL + d] = f2bf(y);
    }
}

// ---------------- launch ----------------
extern "C" void kernel_launch(void* const* d_in, const int* in_sizes, int n_in,
                              void* d_out, int out_size, void* d_ws, size_t ws_size,
                              hipStream_t stream) {
    const float* x       = (const float*)d_in[0];
    const float* W_in    = (const float*)d_in[1];
    const float* b_in    = (const float*)d_in[2];
    const float* W_B     = (const float*)d_in[3];
    const float* b_B     = (const float*)d_in[4];
    const float* W_C     = (const float*)d_in[5];
    const float* b_C     = (const float*)d_in[6];
    const float* W_delta = (const float*)d_in[7];
    const float* b_delta = (const float*)d_in[8];
    const float* W_out   = (const float*)d_in[9];
    const float* b_out   = (const float*)d_in[10];
    const float* A_log   = (const float*)d_in[11];
    const float* Dvec    = (const float*)d_in[12];
    float* out = (float*)d_out;

    char* p = (char*)d_ws;
    auto alloc = [&](size_t bytes) {
        char* r = p;
        p += (bytes + 255) & ~(size_t)255;
        return r;
    };
    unsigned short* xb    = (unsigned short*)alloc((size_t)M_TOT * D_MODEL * 2);
    unsigned short* Wint  = (unsigned short*)alloc((size_t)2 * D_MODEL * D_MODEL * 2);
    unsigned short* WdBC  = (unsigned short*)alloc((size_t)N_DBC * D_MODEL * 2);
    unsigned short* Wot   = (unsigned short*)alloc((size_t)D_MODEL * D_MODEL * 2);
    float*          bdbc  = (float*)alloc((size_t)N_DBC * 4);
    unsigned short* xm_b  = (unsigned short*)alloc((size_t)M_TOT * D_MODEL * 2);
    unsigned short* gate_b= (unsigned short*)alloc((size_t)M_TOT * D_MODEL * 2);
    unsigned short* dlt_b = (unsigned short*)alloc((size_t)M_TOT * D_MODEL * 2);
    float*          Bm    = (float*)alloc((size_t)M_TOT * D_STATE * 4);
    float*          Cm    = (float*)alloc((size_t)M_TOT * D_STATE * 4);
    float*          A_cl  = (float*)alloc((size_t)D_STATE * D_MODEL * 4);
    float*          h_end = (float*)alloc((size_t)BB * NCHUNK * D_STATE * D_MODEL * 4);
    float*          Aprod = (float*)alloc((size_t)BB * NCHUNK * D_STATE * D_MODEL * 4);
    float*          h_in  = (float*)alloc((size_t)BB * NCHUNK * D_STATE * D_MODEL * 4);
    unsigned short* ymid  = (unsigned short*)alloc((size_t)M_TOT * D_MODEL * 2);

    // prep
    k_convert_x<<<(M_TOT * D_MODEL / 4 + 255) / 256, 256, 0, stream>>>(x, xb, M_TOT * D_MODEL / 4);
    k_prep_A<<<(D_STATE * D_MODEL + 255) / 256, 256, 0, stream>>>(A_log, A_cl, D_STATE * D_MODEL);
    k_transpose_bf16<<<dim3(2 * D_MODEL / 32, D_MODEL / 32), 256, 0, stream>>>(W_in, Wint, D_MODEL, 2 * D_MODEL);
    k_transpose_bf16<<<dim3(D_MODEL / 32, D_MODEL / 32), 256, 0, stream>>>(W_delta, WdBC, D_MODEL, D_MODEL);
    k_fill_bc<<<(128 * D_MODEL + 255) / 256, 256, 0, stream>>>(W_B, W_C, WdBC);
    k_bias_dbc<<<(N_DBC + 255) / 256, 256, 0, stream>>>(b_delta, b_B, b_C, bdbc);
    k_transpose_bf16<<<dim3(D_MODEL / 32, D_MODEL / 32), 256, 0, stream>>>(W_out, Wot, D_MODEL, D_MODEL);

    // in-proj GEMM + silu split (bf16 outputs only)
    k_gemm<0><<<dim3(2 * D_MODEL / 128, M_TOT / 128), 256, 0, stream>>>(
        xb, Wint, b_in, D_MODEL, nullptr, nullptr, xm_b, gate_b);
    // delta + B + C fused GEMM
    k_gemm<1><<<dim3(N_DBC / 128, M_TOT / 128), 256, 0, stream>>>(
        xm_b, WdBC, bdbc, D_MODEL, Bm, Cm, dlt_b, nullptr);
    // chunked scan
    k_scanA<<<dim3(D_MODEL / 256, NCHUNK, BB), 256, 0, stream>>>(dlt_b, xm_b, Bm, A_cl, h_end, Aprod);
    k_scanB<<<(BB * D_STATE * D_MODEL) / 256, 256, 0, stream>>>(h_end, Aprod, h_in);
    k_scanC<<<dim3(D_MODEL / 256, NCHUNK, BB), 256, 0, stream>>>(
        dlt_b, xm_b, Bm, Cm, A_cl, h_in, Dvec, gate_b, ymid);
    // out-proj GEMM + clip
    k_gemm<2><<<dim3(D_MODEL / 128, M_TOT / 128), 256, 0, stream>>>(
        ymid, Wot, b_out, D_MODEL, out, nullptr, nullptr, nullptr);
}

// Round 5
// 214.949 us; speedup vs baseline: 1.3091x; 1.0425x over previous
//
#include <hip/hip_runtime.h>
#include <hip/hip_bf16.h>
#include <cstdint>
#include <cstddef>

#define D_MODEL 768
#define D_STATE 16
#define BB      4
#define LL      2048
#define M_TOT   (BB*LL)      // 8192
#define NCHUNK  64
#define LCH     (LL/NCHUNK)  // 32
#define N_DBC   896          // 768 delta + 16 B + 16 C + 96 pad

typedef __attribute__((ext_vector_type(8))) short bf16x8;
typedef __attribute__((ext_vector_type(4))) float f32x4;

__device__ __forceinline__ float clampf_(float x, float lo, float hi) {
    return fminf(fmaxf(x, lo), hi);
}
__device__ __forceinline__ float siluf_(float x) {
    return x / (1.f + __expf(-x));
}
// f32 -> bf16 round-to-nearest-even, as raw u16
__device__ __forceinline__ unsigned short f2bf(float f) {
    unsigned u = __float_as_uint(f);
    u += 0x7fffu + ((u >> 16) & 1u);
    return (unsigned short)(u >> 16);
}
__device__ __forceinline__ float bf2f(unsigned short u) {
    return __uint_as_float(((unsigned)u) << 16);
}
// async global->LDS, 16 bytes per lane; lds base must be wave-uniform
__device__ __forceinline__ void gload16(void* lds, const void* g) {
    __builtin_amdgcn_global_load_lds(
        (const __attribute__((address_space(1))) void*)g,
        (__attribute__((address_space(3))) void*)lds, 16, 0, 0);
}

// ---------------- prep kernels ----------------

__global__ __launch_bounds__(256) void k_convert_x(const float* __restrict__ x,
                                                   unsigned short* __restrict__ xb, int n4) {
    int i = blockIdx.x * 256 + threadIdx.x;
    if (i >= n4) return;
    float4 v = ((const float4*)x)[i];
    ushort4 o;
    o.x = f2bf(v.x); o.y = f2bf(v.y); o.z = f2bf(v.z); o.w = f2bf(v.w);
    ((ushort4*)xb)[i] = o;
}

__global__ __launch_bounds__(256) void k_prep_A(const float* __restrict__ A_log,
                                                float* __restrict__ A_cl, int n) {
    int i = blockIdx.x * 256 + threadIdx.x;
    if (i < n) A_cl[i] = clampf_(-__expf(A_log[i]), -5.f, -0.1f);
}

// transpose R x C f32 -> C x R bf16 (R,C multiples of 32); dst row stride = R
__global__ __launch_bounds__(256) void k_transpose_bf16(const float* __restrict__ src,
                                                        unsigned short* __restrict__ dst,
                                                        int R, int C) {
    __shared__ float tile[32][33];
    int tx = threadIdx.x & 31, ty = threadIdx.x >> 5;
    int c0 = blockIdx.x * 32, r0 = blockIdx.y * 32;
    #pragma unroll
    for (int rr = ty; rr < 32; rr += 8)
        tile[rr][tx] = src[(size_t)(r0 + rr) * C + c0 + tx];
    __syncthreads();
    #pragma unroll
    for (int rr = ty; rr < 32; rr += 8)
        dst[(size_t)(c0 + rr) * R + r0 + tx] = f2bf(tile[tx][rr]);
}

// rows 768..895 of WdBC: W_B^T, W_C^T, zero-pad
__global__ __launch_bounds__(256) void k_fill_bc(const float* __restrict__ W_B,
                                                 const float* __restrict__ W_C,
                                                 unsigned short* __restrict__ WdBC) {
    int idx = blockIdx.x * 256 + threadIdx.x;     // 128*768
    if (idx >= 128 * D_MODEL) return;
    int r = idx / D_MODEL + D_MODEL, k = idx % D_MODEL;
    unsigned short v = 0;
    if (r < D_MODEL + 16)       v = f2bf(W_B[k * 16 + (r - D_MODEL)]);
    else if (r < D_MODEL + 32)  v = f2bf(W_C[k * 16 + (r - D_MODEL - 16)]);
    WdBC[(size_t)r * D_MODEL + k] = v;
}

__global__ __launch_bounds__(256) void k_bias_dbc(const float* __restrict__ b_delta,
                                                  const float* __restrict__ b_B,
                                                  const float* __restrict__ b_C,
                                                  float* __restrict__ bias) {
    int i = blockIdx.x * 256 + threadIdx.x;
    if (i >= N_DBC) return;
    float v = 0.f;
    if (i < D_MODEL)            v = b_delta[i];
    else if (i < D_MODEL + 16)  v = b_B[i - D_MODEL];
    else if (i < D_MODEL + 32)  v = b_C[i - D_MODEL - 16];
    bias[i] = v;
}

// ---------------- main bf16 MFMA GEMM (2-phase prefetch, XCD swizzle) ----------------
// C[M,N] = A[M,K](bf16) * Bt[N,K](bf16)^T + bias, fused epilogue.
// 1D grid, gx = N/128. nwg must be divisible by 8 for the swizzle (guarded).
// EPI 0: W_in   -> col<768: xm_b=silu bf16; col>=768: gate_b=silu bf16
// EPI 1: WdBC   -> col<768: dlt_b=clip(softplus+1e-4) bf16; 768..783: Bm f32; 784..799: Cm f32
// EPI 2: W_out  -> out_f = clip(v,-10,10) f32
template<int EPI>
__global__ __launch_bounds__(256) void k_gemm(const unsigned short* __restrict__ A,
                                              const unsigned short* __restrict__ Bt,
                                              const float* __restrict__ bias,
                                              int K, int gx,
                                              float* __restrict__ out_f,
                                              float* __restrict__ out_f2,
                                              unsigned short* __restrict__ out_b0,
                                              unsigned short* __restrict__ out_b1) {
    __shared__ __align__(16) unsigned short As[2][128 * 32];
    __shared__ __align__(16) unsigned short Bs[2][128 * 32];
    const int tid = threadIdx.x;
    const int wave = tid >> 6, lane = tid & 63;
    const int wm = wave >> 1, wn = wave & 1;

    // bijective XCD swizzle (m204 form, r==0 case): consecutive swz ids stay
    // on one XCD chunk -> A-panel L2 reuse.
    const int nwg = gridDim.x;
    const int wg = blockIdx.x;
    int swz = wg;
    if ((nwg & 7) == 0) {
        const int q = nwg >> 3;
        swz = (wg & 7) * q + (wg >> 3);
    }
    const int bx = swz % gx, by = swz / gx;
    const int m0 = by * 128, n0 = bx * 128;
    const int lr = lane & 15, lk = (lane >> 4) * 8;

    f32x4 acc[4][4] = {};

    auto stage = [&](int buf, int kt) {
        #pragma unroll
        for (int p = 0; p < 2; ++p) {
            int ci = p * 256 + wave * 64 + lane;     // 0..511
            int row = ci >> 2, k8 = (ci & 3) * 8;
            gload16(&As[buf][(p * 256 + wave * 64) * 8],
                    &A [(size_t)(m0 + row) * K + kt + k8]);
            gload16(&Bs[buf][(p * 256 + wave * 64) * 8],
                    &Bt[(size_t)(n0 + row) * K + kt + k8]);
        }
    };
    auto compute = [&](int buf) {
        bf16x8 af[4], bfr[4];
        #pragma unroll
        for (int mt = 0; mt < 4; ++mt)
            af[mt] = *(const bf16x8*)&As[buf][(wm * 64 + mt * 16 + lr) * 32 + lk];
        #pragma unroll
        for (int nt = 0; nt < 4; ++nt)
            bfr[nt] = *(const bf16x8*)&Bs[buf][(wn * 64 + nt * 16 + lr) * 32 + lk];
        #pragma unroll
        for (int mt = 0; mt < 4; ++mt)
            #pragma unroll
            for (int nt = 0; nt < 4; ++nt)
                acc[mt][nt] = __builtin_amdgcn_mfma_f32_16x16x32_bf16(
                    af[mt], bfr[nt], acc[mt][nt], 0, 0, 0);
    };

    // prologue: stage tile 0, wait (syncthreads drains vmcnt before s_barrier)
    stage(0, 0);
    __syncthreads();
    int cur = 0;
    for (int kt = 32; kt < K; kt += 32) {
        stage(cur ^ 1, kt);    // issue next-tile loads (in flight across compute)
        compute(cur);          // ds_read + 16 MFMA on current tile
        __syncthreads();       // drains vmcnt(0): next tile ready; reads done
        cur ^= 1;
    }
    compute(cur);              // last tile, no prefetch

    #pragma unroll
    for (int mt = 0; mt < 4; ++mt) {
        int row = m0 + wm * 64 + mt * 16 + (lane >> 4) * 4;
        #pragma unroll
        for (int nt = 0; nt < 4; ++nt) {
            int col = n0 + wn * 64 + nt * 16 + (lane & 15);
            #pragma unroll
            for (int i = 0; i < 4; ++i) {
                int r = row + i;
                float v = acc[mt][nt][i] + bias[col];
                if (EPI == 0) {
                    float s = siluf_(v);
                    if (col < D_MODEL) out_b0[(size_t)r * D_MODEL + col] = f2bf(s);
                    else               out_b1[(size_t)r * D_MODEL + (col - D_MODEL)] = f2bf(s);
                } else if (EPI == 1) {
                    if (col < D_MODEL) {
                        float sp = (v > 20.f) ? v : log1pf(__expf(v));
                        out_b0[(size_t)r * D_MODEL + col] = f2bf(clampf_(sp + 1e-4f, 1e-4f, 1.f));
                    } else if (col < D_MODEL + 16) {
                        out_f[(size_t)r * D_STATE + (col - D_MODEL)] = v;
                    } else if (col < D_MODEL + 32) {
                        out_f2[(size_t)r * D_STATE + (col - D_MODEL - 16)] = v;
                    }
                } else {
                    out_f[(size_t)r * D_MODEL + col] = clampf_(v, -10.f, 10.f);
                }
            }
        }
    }
}

// ---------------- chunked selective scan ----------------
// pass A: per (b, chunk, d) local scan from h=0; emit h_end, Aprod
__global__ __launch_bounds__(256) void k_scanA(const unsigned short* __restrict__ dlt,
                                               const unsigned short* __restrict__ xm,
                                               const float* __restrict__ Bm,
                                               const float* __restrict__ A_cl,
                                               float* __restrict__ h_end,
                                               float* __restrict__ Aprod) {
    const int d = blockIdx.x * 256 + threadIdx.x;
    const int c = blockIdx.y, b = blockIdx.z;
    __shared__ float Bsh[LCH][D_STATE];
    const int rowbase = b * LL + c * LCH;
    for (int i = threadIdx.x; i < LCH * D_STATE; i += 256)
        ((float*)Bsh)[i] = Bm[(size_t)rowbase * D_STATE + i];
    __syncthreads();

    float Asv[16], h[16], ap[16];
    #pragma unroll
    for (int s = 0; s < 16; ++s) {
        Asv[s] = A_cl[s * D_MODEL + d];
        h[s] = 0.f; ap[s] = 1.f;
    }
    for (int tt = 0; tt < LCH; ++tt) {
        const size_t rowoff = (size_t)(rowbase + tt);
        float dltv = bf2f(dlt[rowoff * D_MODEL + d]);
        float xv   = bf2f(xm [rowoff * D_MODEL + d]);
        float dx = dltv * xv;
        #pragma unroll
        for (int s = 0; s < 16; ++s) {
            float dA  = __expf(fmaxf(dltv * Asv[s], -2.f));
            float dBu = clampf_(dx * Bsh[tt][s], -5.f, 5.f);
            h[s] = clampf_(fmaf(dA, h[s], dBu), -100.f, 100.f);
            ap[s] *= dA;
        }
    }
    const size_t off = (((size_t)b * NCHUNK + c) * D_STATE) * D_MODEL + d;
    #pragma unroll
    for (int s = 0; s < 16; ++s) {
        h_end[off + (size_t)s * D_MODEL] = h[s];
        Aprod[off + (size_t)s * D_MODEL] = ap[s];
    }
}

// pass B: carry propagation across chunks per (b,s,d)
__global__ __launch_bounds__(256) void k_scanB(const float* __restrict__ h_end,
                                               const float* __restrict__ Aprod,
                                               float* __restrict__ h_in) {
    const int idx = blockIdx.x * 256 + threadIdx.x;  // 4*16*768 = 49152
    const int d = idx % D_MODEL;
    const int rest = idx / D_MODEL;
    const int s = rest & 15, b = rest >> 4;
    float hc = 0.f;
    for (int c = 0; c < NCHUNK; ++c) {
        const size_t off = (((size_t)b * NCHUNK + c) * D_STATE + s) * D_MODEL + d;
        h_in[off] = hc;
        hc = Aprod[off] * hc + h_end[off];
    }
}

// pass C: replay with true carry, fuse y = clip(sum_s h*C) + xm*D, * gate -> bf16
__global__ __launch_bounds__(256) void k_scanC(const unsigned short* __restrict__ dlt,
                                               const unsigned short* __restrict__ xm,
                                               const float* __restrict__ Bm,
                                               const float* __restrict__ Cm,
                                               const float* __restrict__ A_cl,
                                               const float* __restrict__ h_in,
                                               const float* __restrict__ Dvec,
                                               const unsigned short* __restrict__ gate,
                                               unsigned short* __restrict__ ymid) {
    const int d = blockIdx.x * 256 + threadIdx.x;
    const int c = blockIdx.y, b = blockIdx.z;
    __shared__ float Bsh[LCH][D_STATE];
    __shared__ float Csh[LCH][D_STATE];
    const int rowbase = b * LL + c * LCH;
    for (int i = threadIdx.x; i < LCH * D_STATE; i += 256) {
        ((float*)Bsh)[i] = Bm[(size_t)rowbase * D_STATE + i];
        ((float*)Csh)[i] = Cm[(size_t)rowbase * D_STATE + i];
    }
    __syncthreads();

    float Asv[16], h[16];
    const size_t coff = (((size_t)b * NCHUNK + c) * D_STATE) * D_MODEL + d;
    #pragma unroll
    for (int s = 0; s < 16; ++s) {
        Asv[s] = A_cl[s * D_MODEL + d];
        h[s] = h_in[coff + (size_t)s * D_MODEL];
    }
    const float Dv = Dvec[d];
    for (int tt = 0; tt < LCH; ++tt) {
        const size_t rowoff = (size_t)(rowbase + tt);
        float dltv = bf2f(dlt[rowoff * D_MODEL + d]);
        float xv   = bf2f(xm [rowoff * D_MODEL + d]);
        float dx = dltv * xv;
        float y = 0.f;
        #pragma unroll
        for (int s = 0; s < 16; ++s) {
            float dA  = __expf(fmaxf(dltv * Asv[s], -2.f));
            float dBu = clampf_(dx * Bsh[tt][s], -5.f, 5.f);
            h[s] = clampf_(fmaf(dA, h[s], dBu), -100.f, 100.f);
            y = fmaf(h[s], Csh[tt][s], y);
        }
        y = clampf_(y, -10.f, 10.f);
        y = fmaf(xv, Dv, y);
        y *= bf2f(gate[rowoff * D_MODEL + d]);
        ymid[rowoff * D_MODEL + d] = f2bf(y);
    }
}

// ---------------- launch ----------------
extern "C" void kernel_launch(void* const* d_in, const int* in_sizes, int n_in,
                              void* d_out, int out_size, void* d_ws, size_t ws_size,
                              hipStream_t stream) {
    const float* x       = (const float*)d_in[0];
    const float* W_in    = (const float*)d_in[1];
    const float* b_in    = (const float*)d_in[2];
    const float* W_B     = (const float*)d_in[3];
    const float* b_B     = (const float*)d_in[4];
    const float* W_C     = (const float*)d_in[5];
    const float* b_C     = (const float*)d_in[6];
    const float* W_delta = (const float*)d_in[7];
    const float* b_delta = (const float*)d_in[8];
    const float* W_out   = (const float*)d_in[9];
    const float* b_out   = (const float*)d_in[10];
    const float* A_log   = (const float*)d_in[11];
    const float* Dvec    = (const float*)d_in[12];
    float* out = (float*)d_out;

    char* p = (char*)d_ws;
    auto alloc = [&](size_t bytes) {
        char* r = p;
        p += (bytes + 255) & ~(size_t)255;
        return r;
    };
    unsigned short* xb    = (unsigned short*)alloc((size_t)M_TOT * D_MODEL * 2);
    unsigned short* Wint  = (unsigned short*)alloc((size_t)2 * D_MODEL * D_MODEL * 2);
    unsigned short* WdBC  = (unsigned short*)alloc((size_t)N_DBC * D_MODEL * 2);
    unsigned short* Wot   = (unsigned short*)alloc((size_t)D_MODEL * D_MODEL * 2);
    float*          bdbc  = (float*)alloc((size_t)N_DBC * 4);
    unsigned short* xm_b  = (unsigned short*)alloc((size_t)M_TOT * D_MODEL * 2);
    unsigned short* gate_b= (unsigned short*)alloc((size_t)M_TOT * D_MODEL * 2);
    unsigned short* dlt_b = (unsigned short*)alloc((size_t)M_TOT * D_MODEL * 2);
    float*          Bm    = (float*)alloc((size_t)M_TOT * D_STATE * 4);
    float*          Cm    = (float*)alloc((size_t)M_TOT * D_STATE * 4);
    float*          A_cl  = (float*)alloc((size_t)D_STATE * D_MODEL * 4);
    float*          h_end = (float*)alloc((size_t)BB * NCHUNK * D_STATE * D_MODEL * 4);
    float*          Aprod = (float*)alloc((size_t)BB * NCHUNK * D_STATE * D_MODEL * 4);
    float*          h_in  = (float*)alloc((size_t)BB * NCHUNK * D_STATE * D_MODEL * 4);
    unsigned short* ymid  = (unsigned short*)alloc((size_t)M_TOT * D_MODEL * 2);

    // prep
    k_convert_x<<<(M_TOT * D_MODEL / 4 + 255) / 256, 256, 0, stream>>>(x, xb, M_TOT * D_MODEL / 4);
    k_prep_A<<<(D_STATE * D_MODEL + 255) / 256, 256, 0, stream>>>(A_log, A_cl, D_STATE * D_MODEL);
    k_transpose_bf16<<<dim3(2 * D_MODEL / 32, D_MODEL / 32), 256, 0, stream>>>(W_in, Wint, D_MODEL, 2 * D_MODEL);
    k_transpose_bf16<<<dim3(D_MODEL / 32, D_MODEL / 32), 256, 0, stream>>>(W_delta, WdBC, D_MODEL, D_MODEL);
    k_fill_bc<<<(128 * D_MODEL + 255) / 256, 256, 0, stream>>>(W_B, W_C, WdBC);
    k_bias_dbc<<<(N_DBC + 255) / 256, 256, 0, stream>>>(b_delta, b_B, b_C, bdbc);
    k_transpose_bf16<<<dim3(D_MODEL / 32, D_MODEL / 32), 256, 0, stream>>>(W_out, Wot, D_MODEL, D_MODEL);

    // in-proj GEMM + silu split (bf16 outputs only); 1D grid: gx=12, gy=64 -> 768
    k_gemm<0><<<dim3((2 * D_MODEL / 128) * (M_TOT / 128)), 256, 0, stream>>>(
        xb, Wint, b_in, D_MODEL, 2 * D_MODEL / 128, nullptr, nullptr, xm_b, gate_b);
    // delta + B + C fused GEMM; gx=7, gy=64 -> 448
    k_gemm<1><<<dim3((N_DBC / 128) * (M_TOT / 128)), 256, 0, stream>>>(
        xm_b, WdBC, bdbc, D_MODEL, N_DBC / 128, Bm, Cm, dlt_b, nullptr);
    // chunked scan
    k_scanA<<<dim3(D_MODEL / 256, NCHUNK, BB), 256, 0, stream>>>(dlt_b, xm_b, Bm, A_cl, h_end, Aprod);
    k_scanB<<<(BB * D_STATE * D_MODEL) / 256, 256, 0, stream>>>(h_end, Aprod, h_in);
    k_scanC<<<dim3(D_MODEL / 256, NCHUNK, BB), 256, 0, stream>>>(
        dlt_b, xm_b, Bm, Cm, A_cl, h_in, Dvec, gate_b, ymid);
    // out-proj GEMM + clip; gx=6, gy=64 -> 384
    k_gemm<2><<<dim3((D_MODEL / 128) * (M_TOT / 128)), 256, 0, stream>>>(
        ymid, Wot, b_out, D_MODEL, D_MODEL / 128, out, nullptr, nullptr, nullptr);
}

// Round 7
// 212.503 us; speedup vs baseline: 1.3242x; 1.0115x over previous
//
#include <hip/hip_runtime.h>
#include <hip/hip_bf16.h>
#include <cstdint>
#include <cstddef>

#define D_MODEL 768
#define D_STATE 16
#define BB      4
#define LL      2048
#define M_TOT   (BB*LL)      // 8192
#define NCHUNK  64
#define LCH     (LL/NCHUNK)  // 32
#define N_DBC   896          // 768 delta + 16 B + 16 C + 96 pad

typedef __attribute__((ext_vector_type(8))) short bf16x8;
typedef __attribute__((ext_vector_type(4))) float f32x4;

__device__ __forceinline__ float clampf_(float x, float lo, float hi) {
    return fminf(fmaxf(x, lo), hi);
}
__device__ __forceinline__ float siluf_(float x) {
    return x / (1.f + __expf(-x));
}
// f32 -> bf16 round-to-nearest-even, as raw u16
__device__ __forceinline__ unsigned short f2bf(float f) {
    unsigned u = __float_as_uint(f);
    u += 0x7fffu + ((u >> 16) & 1u);
    return (unsigned short)(u >> 16);
}
__device__ __forceinline__ float bf2f(unsigned short u) {
    return __uint_as_float(((unsigned)u) << 16);
}
// async global->LDS, 16 bytes per lane; lds base must be wave-uniform
__device__ __forceinline__ void gload16(void* lds, const void* g) {
    __builtin_amdgcn_global_load_lds(
        (const __attribute__((address_space(1))) void*)g,
        (__attribute__((address_space(3))) void*)lds, 16, 0, 0);
}

// ---------------- prep kernels ----------------

__global__ __launch_bounds__(256) void k_convert_x(const float* __restrict__ x,
                                                   unsigned short* __restrict__ xb, int n4) {
    int i = blockIdx.x * 256 + threadIdx.x;
    if (i >= n4) return;
    float4 v = ((const float4*)x)[i];
    ushort4 o;
    o.x = f2bf(v.x); o.y = f2bf(v.y); o.z = f2bf(v.z); o.w = f2bf(v.w);
    ((ushort4*)xb)[i] = o;
}

__global__ __launch_bounds__(256) void k_prep_A(const float* __restrict__ A_log,
                                                float* __restrict__ A_cl, int n) {
    int i = blockIdx.x * 256 + threadIdx.x;
    if (i < n) A_cl[i] = clampf_(-__expf(A_log[i]), -5.f, -0.1f);
}

// transpose R x C f32 -> C x R bf16 (R,C multiples of 32); dst row stride = R
__global__ __launch_bounds__(256) void k_transpose_bf16(const float* __restrict__ src,
                                                        unsigned short* __restrict__ dst,
                                                        int R, int C) {
    __shared__ float tile[32][33];
    int tx = threadIdx.x & 31, ty = threadIdx.x >> 5;
    int c0 = blockIdx.x * 32, r0 = blockIdx.y * 32;
    #pragma unroll
    for (int rr = ty; rr < 32; rr += 8)
        tile[rr][tx] = src[(size_t)(r0 + rr) * C + c0 + tx];
    __syncthreads();
    #pragma unroll
    for (int rr = ty; rr < 32; rr += 8)
        dst[(size_t)(c0 + rr) * R + r0 + tx] = f2bf(tile[tx][rr]);
}

// rows 768..895 of WdBC: W_B^T, W_C^T, zero-pad
__global__ __launch_bounds__(256) void k_fill_bc(const float* __restrict__ W_B,
                                                 const float* __restrict__ W_C,
                                                 unsigned short* __restrict__ WdBC) {
    int idx = blockIdx.x * 256 + threadIdx.x;     // 128*768
    if (idx >= 128 * D_MODEL) return;
    int r = idx / D_MODEL + D_MODEL, k = idx % D_MODEL;
    unsigned short v = 0;
    if (r < D_MODEL + 16)       v = f2bf(W_B[k * 16 + (r - D_MODEL)]);
    else if (r < D_MODEL + 32)  v = f2bf(W_C[k * 16 + (r - D_MODEL - 16)]);
    WdBC[(size_t)r * D_MODEL + k] = v;
}

__global__ __launch_bounds__(256) void k_bias_dbc(const float* __restrict__ b_delta,
                                                  const float* __restrict__ b_B,
                                                  const float* __restrict__ b_C,
                                                  float* __restrict__ bias) {
    int i = blockIdx.x * 256 + threadIdx.x;
    if (i >= N_DBC) return;
    float v = 0.f;
    if (i < D_MODEL)            v = b_delta[i];
    else if (i < D_MODEL + 16)  v = b_B[i - D_MODEL];
    else if (i < D_MODEL + 32)  v = b_C[i - D_MODEL - 16];
    bias[i] = v;
}

// ---------------- main bf16 MFMA GEMM ----------------
// 3-deep pipeline, counted vmcnt (T3/T4), raw s_barrier, XCD swizzle.
// C[M,N] = A[M,K](bf16) * Bt[N,K](bf16)^T + bias, fused epilogue.
// Requires K/32 >= 4 (here K=768, NT=24).
template<int EPI>
__global__ __launch_bounds__(256) void k_gemm(const unsigned short* __restrict__ A,
                                              const unsigned short* __restrict__ Bt,
                                              const float* __restrict__ bias,
                                              int K, int gx,
                                              float* __restrict__ out_f,
                                              float* __restrict__ out_f2,
                                              unsigned short* __restrict__ out_b0,
                                              unsigned short* __restrict__ out_b1) {
    __shared__ __align__(16) unsigned short As[3][128 * 32];
    __shared__ __align__(16) unsigned short Bs[3][128 * 32];
    const int tid = threadIdx.x;
    const int wave = tid >> 6, lane = tid & 63;
    const int wm = wave >> 1, wn = wave & 1;

    // bijective XCD swizzle (m204, r==0 case)
    const int nwg = gridDim.x;
    const int wg = blockIdx.x;
    int swz = wg;
    if ((nwg & 7) == 0) {
        const int q = nwg >> 3;
        swz = (wg & 7) * q + (wg >> 3);
    }
    const int bx = swz % gx, by = swz / gx;
    const int m0 = by * 128, n0 = bx * 128;
    const int lr = lane & 15, lk = (lane >> 4) * 8;
    const int NT = K >> 5;   // K-steps of 32

    // per-thread staging base pointers (2 chunks each for A and B)
    const int ci0 = wave * 64 + lane;            // p=0 chunk id
    const int ci1 = 256 + ci0;                   // p=1
    const unsigned short* ga0 = &A [(size_t)(m0 + (ci0 >> 2)) * K + (ci0 & 3) * 8];
    const unsigned short* ga1 = &A [(size_t)(m0 + (ci1 >> 2)) * K + (ci1 & 3) * 8];
    const unsigned short* gb0 = &Bt[(size_t)(n0 + (ci0 >> 2)) * K + (ci0 & 3) * 8];
    const unsigned short* gb1 = &Bt[(size_t)(n0 + (ci1 >> 2)) * K + (ci1 & 3) * 8];
    const int ldsOff0 = (wave * 64) * 8;         // shorts
    const int ldsOff1 = (256 + wave * 64) * 8;

    f32x4 acc[4][4] = {};

    auto stage = [&](int buf, int kt) {
        gload16(&As[buf][ldsOff0], ga0 + kt);
        gload16(&As[buf][ldsOff1], ga1 + kt);
        gload16(&Bs[buf][ldsOff0], gb0 + kt);
        gload16(&Bs[buf][ldsOff1], gb1 + kt);
    };
    auto compute = [&](int buf) {
        bf16x8 af[4], bfr[4];
        #pragma unroll
        for (int mt = 0; mt < 4; ++mt)
            af[mt] = *(const bf16x8*)&As[buf][(wm * 64 + mt * 16 + lr) * 32 + lk];
        #pragma unroll
        for (int nt = 0; nt < 4; ++nt)
            bfr[nt] = *(const bf16x8*)&Bs[buf][(wn * 64 + nt * 16 + lr) * 32 + lk];
        #pragma unroll
        for (int mt = 0; mt < 4; ++mt)
            #pragma unroll
            for (int nt = 0; nt < 4; ++nt)
                acc[mt][nt] = __builtin_amdgcn_mfma_f32_16x16x32_bf16(
                    af[mt], bfr[nt], acc[mt][nt], 0, 0, 0);
    };

    // prologue: 3 tiles in flight, wait for tile 0 (12 -> 8 outstanding)
    stage(0, 0);
    stage(1, 32);
    stage(2, 64);
    asm volatile("s_waitcnt vmcnt(8)" ::: "memory");
    __builtin_amdgcn_sched_barrier(0);
    __builtin_amdgcn_s_barrier();

    // steady state: tiles t+1, t+2 in flight while computing t
    for (int t = 0; t < NT - 3; ++t) {
        compute(t % 3);
        asm volatile("s_waitcnt lgkmcnt(0)" ::: "memory");  // my LDS reads done
        __builtin_amdgcn_sched_barrier(0);
        __builtin_amdgcn_s_barrier();                        // all reads of buf t done
        stage(t % 3, (t + 3) << 5);                          // overwrite with tile t+3
        asm volatile("s_waitcnt vmcnt(8)" ::: "memory");     // tile t+1 landed (mine)
        __builtin_amdgcn_sched_barrier(0);
        __builtin_amdgcn_s_barrier();                        // tile t+1 landed (all)
    }
    // tail: no more staging; drain 4 -> 0
    compute((NT - 3) % 3);
    asm volatile("s_waitcnt vmcnt(4)" ::: "memory");
    __builtin_amdgcn_sched_barrier(0);
    __builtin_amdgcn_s_barrier();
    compute((NT - 2) % 3);
    asm volatile("s_waitcnt vmcnt(0)" ::: "memory");
    __builtin_amdgcn_sched_barrier(0);
    __builtin_amdgcn_s_barrier();
    compute((NT - 1) % 3);

    #pragma unroll
    for (int mt = 0; mt < 4; ++mt) {
        int row = m0 + wm * 64 + mt * 16 + (lane >> 4) * 4;
        #pragma unroll
        for (int nt = 0; nt < 4; ++nt) {
            int col = n0 + wn * 64 + nt * 16 + (lane & 15);
            #pragma unroll
            for (int i = 0; i < 4; ++i) {
                int r = row + i;
                float v = acc[mt][nt][i] + bias[col];
                if (EPI == 0) {
                    float s = siluf_(v);
                    if (col < D_MODEL) out_b0[(size_t)r * D_MODEL + col] = f2bf(s);
                    else               out_b1[(size_t)r * D_MODEL + (col - D_MODEL)] = f2bf(s);
                } else if (EPI == 1) {
                    if (col < D_MODEL) {
                        float sp = (v > 20.f) ? v : log1pf(__expf(v));
                        out_b0[(size_t)r * D_MODEL + col] = f2bf(clampf_(sp + 1e-4f, 1e-4f, 1.f));
                    } else if (col < D_MODEL + 16) {
                        out_f[(size_t)r * D_STATE + (col - D_MODEL)] = v;
                    } else if (col < D_MODEL + 32) {
                        out_f2[(size_t)r * D_STATE + (col - D_MODEL - 16)] = v;
                    }
                } else {
                    out_f[(size_t)r * D_MODEL + col] = clampf_(v, -10.f, 10.f);
                }
            }
        }
    }
}

// ---------------- chunked selective scan ----------------
// pass A: per (b, chunk, d) local scan from h=0; emit h_end, Aprod
__global__ __launch_bounds__(256) void k_scanA(const unsigned short* __restrict__ dlt,
                                               const unsigned short* __restrict__ xm,
                                               const float* __restrict__ Bm,
                                               const float* __restrict__ A_cl,
                                               float* __restrict__ h_end,
                                               float* __restrict__ Aprod) {
    const int d = blockIdx.x * 256 + threadIdx.x;
    const int c = blockIdx.y, b = blockIdx.z;
    __shared__ float Bsh[LCH][D_STATE];
    const int rowbase = b * LL + c * LCH;
    for (int i = threadIdx.x; i < LCH * D_STATE; i += 256)
        ((float*)Bsh)[i] = Bm[(size_t)rowbase * D_STATE + i];
    __syncthreads();

    float Asv[16], h[16], ap[16];
    #pragma unroll
    for (int s = 0; s < 16; ++s) {
        Asv[s] = A_cl[s * D_MODEL + d];
        h[s] = 0.f; ap[s] = 1.f;
    }
    for (int tt = 0; tt < LCH; ++tt) {
        const size_t rowoff = (size_t)(rowbase + tt);
        float dltv = bf2f(dlt[rowoff * D_MODEL + d]);
        float xv   = bf2f(xm [rowoff * D_MODEL + d]);
        float dx = dltv * xv;
        #pragma unroll
        for (int s = 0; s < 16; ++s) {
            float dA  = __expf(fmaxf(dltv * Asv[s], -2.f));
            float dBu = clampf_(dx * Bsh[tt][s], -5.f, 5.f);
            h[s] = clampf_(fmaf(dA, h[s], dBu), -100.f, 100.f);
            ap[s] *= dA;
        }
    }
    const size_t off = (((size_t)b * NCHUNK + c) * D_STATE) * D_MODEL + d;
    #pragma unroll
    for (int s = 0; s < 16; ++s) {
        h_end[off + (size_t)s * D_MODEL] = h[s];
        Aprod[off + (size_t)s * D_MODEL] = ap[s];
    }
}

// pass B: carry propagation across chunks per (b,s,d)
__global__ __launch_bounds__(256) void k_scanB(const float* __restrict__ h_end,
                                               const float* __restrict__ Aprod,
                                               float* __restrict__ h_in) {
    const int idx = blockIdx.x * 256 + threadIdx.x;  // 4*16*768 = 49152
    const int d = idx % D_MODEL;
    const int rest = idx / D_MODEL;
    const int s = rest & 15, b = rest >> 4;
    float hc = 0.f;
    for (int c = 0; c < NCHUNK; ++c) {
        const size_t off = (((size_t)b * NCHUNK + c) * D_STATE + s) * D_MODEL + d;
        h_in[off] = hc;
        hc = Aprod[off] * hc + h_end[off];
    }
}

// pass C: replay with true carry, fuse y = clip(sum_s h*C) + xm*D, * gate -> bf16
__global__ __launch_bounds__(256) void k_scanC(const unsigned short* __restrict__ dlt,
                                               const unsigned short* __restrict__ xm,
                                               const float* __restrict__ Bm,
                                               const float* __restrict__ Cm,
                                               const float* __restrict__ A_cl,
                                               const float* __restrict__ h_in,
                                               const float* __restrict__ Dvec,
                                               const unsigned short* __restrict__ gate,
                                               unsigned short* __restrict__ ymid) {
    const int d = blockIdx.x * 256 + threadIdx.x;
    const int c = blockIdx.y, b = blockIdx.z;
    __shared__ float Bsh[LCH][D_STATE];
    __shared__ float Csh[LCH][D_STATE];
    const int rowbase = b * LL + c * LCH;
    for (int i = threadIdx.x; i < LCH * D_STATE; i += 256) {
        ((float*)Bsh)[i] = Bm[(size_t)rowbase * D_STATE + i];
        ((float*)Csh)[i] = Cm[(size_t)rowbase * D_STATE + i];
    }
    __syncthreads();

    float Asv[16], h[16];
    const size_t coff = (((size_t)b * NCHUNK + c) * D_STATE) * D_MODEL + d;
    #pragma unroll
    for (int s = 0; s < 16; ++s) {
        Asv[s] = A_cl[s * D_MODEL + d];
        h[s] = h_in[coff + (size_t)s * D_MODEL];
    }
    const float Dv = Dvec[d];
    for (int tt = 0; tt < LCH; ++tt) {
        const size_t rowoff = (size_t)(rowbase + tt);
        float dltv = bf2f(dlt[rowoff * D_MODEL + d]);
        float xv   = bf2f(xm [rowoff * D_MODEL + d]);
        float dx = dltv * xv;
        float y = 0.f;
        #pragma unroll
        for (int s = 0; s < 16; ++s) {
            float dA  = __expf(fmaxf(dltv * Asv[s], -2.f));
            float dBu = clampf_(dx * Bsh[tt][s], -5.f, 5.f);
            h[s] = clampf_(fmaf(dA, h[s], dBu), -100.f, 100.f);
            y = fmaf(h[s], Csh[tt][s], y);
        }
        y = clampf_(y, -10.f, 10.f);
        y = fmaf(xv, Dv, y);
        y *= bf2f(gate[rowoff * D_MODEL + d]);
        ymid[rowoff * D_MODEL + d] = f2bf(y);
    }
}

// ---------------- launch ----------------
extern "C" void kernel_launch(void* const* d_in, const int* in_sizes, int n_in,
                              void* d_out, int out_size, void* d_ws, size_t ws_size,
                              hipStream_t stream) {
    const float* x       = (const float*)d_in[0];
    const float* W_in    = (const float*)d_in[1];
    const float* b_in    = (const float*)d_in[2];
    const float* W_B     = (const float*)d_in[3];
    const float* b_B     = (const float*)d_in[4];
    const float* W_C     = (const float*)d_in[5];
    const float* b_C     = (const float*)d_in[6];
    const float* W_delta = (const float*)d_in[7];
    const float* b_delta = (const float*)d_in[8];
    const float* W_out   = (const float*)d_in[9];
    const float* b_out   = (const float*)d_in[10];
    const float* A_log   = (const float*)d_in[11];
    const float* Dvec    = (const float*)d_in[12];
    float* out = (float*)d_out;

    char* p = (char*)d_ws;
    auto alloc = [&](size_t bytes) {
        char* r = p;
        p += (bytes + 255) & ~(size_t)255;
        return r;
    };
    unsigned short* xb    = (unsigned short*)alloc((size_t)M_TOT * D_MODEL * 2);
    unsigned short* Wint  = (unsigned short*)alloc((size_t)2 * D_MODEL * D_MODEL * 2);
    unsigned short* WdBC  = (unsigned short*)alloc((size_t)N_DBC * D_MODEL * 2);
    unsigned short* Wot   = (unsigned short*)alloc((size_t)D_MODEL * D_MODEL * 2);
    float*          bdbc  = (float*)alloc((size_t)N_DBC * 4);
    unsigned short* xm_b  = (unsigned short*)alloc((size_t)M_TOT * D_MODEL * 2);
    unsigned short* gate_b= (unsigned short*)alloc((size_t)M_TOT * D_MODEL * 2);
    unsigned short* dlt_b = (unsigned short*)alloc((size_t)M_TOT * D_MODEL * 2);
    float*          Bm    = (float*)alloc((size_t)M_TOT * D_STATE * 4);
    float*          Cm    = (float*)alloc((size_t)M_TOT * D_STATE * 4);
    float*          A_cl  = (float*)alloc((size_t)D_STATE * D_MODEL * 4);
    float*          h_end = (float*)alloc((size_t)BB * NCHUNK * D_STATE * D_MODEL * 4);
    float*          Aprod = (float*)alloc((size_t)BB * NCHUNK * D_STATE * D_MODEL * 4);
    float*          h_in  = (float*)alloc((size_t)BB * NCHUNK * D_STATE * D_MODEL * 4);
    unsigned short* ymid  = (unsigned short*)alloc((size_t)M_TOT * D_MODEL * 2);

    // prep
    k_convert_x<<<(M_TOT * D_MODEL / 4 + 255) / 256, 256, 0, stream>>>(x, xb, M_TOT * D_MODEL / 4);
    k_prep_A<<<(D_STATE * D_MODEL + 255) / 256, 256, 0, stream>>>(A_log, A_cl, D_STATE * D_MODEL);
    k_transpose_bf16<<<dim3(2 * D_MODEL / 32, D_MODEL / 32), 256, 0, stream>>>(W_in, Wint, D_MODEL, 2 * D_MODEL);
    k_transpose_bf16<<<dim3(D_MODEL / 32, D_MODEL / 32), 256, 0, stream>>>(W_delta, WdBC, D_MODEL, D_MODEL);
    k_fill_bc<<<(128 * D_MODEL + 255) / 256, 256, 0, stream>>>(W_B, W_C, WdBC);
    k_bias_dbc<<<(N_DBC + 255) / 256, 256, 0, stream>>>(b_delta, b_B, b_C, bdbc);
    k_transpose_bf16<<<dim3(D_MODEL / 32, D_MODEL / 32), 256, 0, stream>>>(W_out, Wot, D_MODEL, D_MODEL);

    // in-proj GEMM + silu split; 1D grid: gx=12, 768 blocks
    k_gemm<0><<<dim3((2 * D_MODEL / 128) * (M_TOT / 128)), 256, 0, stream>>>(
        xb, Wint, b_in, D_MODEL, 2 * D_MODEL / 128, nullptr, nullptr, xm_b, gate_b);
    // delta + B + C fused GEMM; gx=7, 448 blocks
    k_gemm<1><<<dim3((N_DBC / 128) * (M_TOT / 128)), 256, 0, stream>>>(
        xm_b, WdBC, bdbc, D_MODEL, N_DBC / 128, Bm, Cm, dlt_b, nullptr);
    // chunked scan
    k_scanA<<<dim3(D_MODEL / 256, NCHUNK, BB), 256, 0, stream>>>(dlt_b, xm_b, Bm, A_cl, h_end, Aprod);
    k_scanB<<<(BB * D_STATE * D_MODEL) / 256, 256, 0, stream>>>(h_end, Aprod, h_in);
    k_scanC<<<dim3(D_MODEL / 256, NCHUNK, BB), 256, 0, stream>>>(
        dlt_b, xm_b, Bm, Cm, A_cl, h_in, Dvec, gate_b, ymid);
    // out-proj GEMM + clip; gx=6, 384 blocks
    k_gemm<2><<<dim3((D_MODEL / 128) * (M_TOT / 128)), 256, 0, stream>>>(
        ymid, Wot, b_out, D_MODEL, D_MODEL / 128, out, nullptr, nullptr, nullptr);
}